// Round 2
// baseline (743.892 us; speedup 1.0000x reference)
//
#include <hip/hip_runtime.h>

// Fused 4-layer MLP (2 -> 1024 -> 512 -> 256 -> 3), N = 262144, fp32 I/O.
// R2: 1024-thread blocks (16 waves), 128 rows/block, acc2 = 64 VGPR/thread,
// phases sequenced so peak live regs <= ~112 -> 4 waves/SIMD occupancy.
// fp16 MFMA 32x32x16, fp32 accumulate, transposed layers D[feat][batch].

typedef _Float16 f16;
typedef f16 f16x8 __attribute__((ext_vector_type(8)));
typedef f16 f16x4 __attribute__((ext_vector_type(4)));
typedef float f32x16 __attribute__((ext_vector_type(16)));

#define MFMA(a, b, c) __builtin_amdgcn_mfma_f32_32x32x16_f16((a), (b), (c), 0, 0, 0)

// ws layout in 16-byte units (f16x8):
//  W1F : [16 jt][64 ks][64 lane]            ->      0 .. 65536
//  W2F : [ 8 jt][32 ks][64 lane]            ->  65536 .. 81920
//  W3F : [16 ks][64 lane]                   ->  81920 .. 82944
//  P0F : [32 k1t][64 lane] (layer1 A frag)  ->  82944 .. 84992
//  B1F : [16 jt][64 lane]                   ->  84992 .. 86016
//  B2F : [ 8 jt][64 lane]                   ->  86016 .. 86528
#define U_W1F 0
#define U_W2F 65536
#define U_W3F 81920
#define U_P0F 82944
#define U_B1F 84992
#define U_B2F 86016
#define U_TOTAL 86528

__global__ void prep_kernel(const float* __restrict__ W0, const float* __restrict__ b0,
                            const float* __restrict__ W1, const float* __restrict__ b1,
                            const float* __restrict__ W2, const float* __restrict__ b2,
                            const float* __restrict__ W3, f16* __restrict__ ws)
{
    int u = blockIdx.x * 256 + threadIdx.x;
    if (u >= U_TOTAL) return;
    int lane = u & 63;
    int l31 = lane & 31;
    int q = lane >> 5;
    f16x8 v;
#pragma unroll
    for (int e = 0; e < 8; ++e) v[e] = (f16)0.f;

    if (u < U_W2F) {                       // W1F: W1 is [1024][512]
        int jt = u >> 12, ks = (u >> 6) & 63;
        int j = jt * 32 + l31;
        int kb = ks * 16 + q * 8;
        const float* p = W1 + (size_t)kb * 512 + j;
#pragma unroll
        for (int e = 0; e < 8; ++e) v[e] = (f16)p[(size_t)e * 512];
    } else if (u < U_W3F) {                // W2F: W2 is [512][256]
        int t = u - U_W2F;
        int jt = t >> 11, ks = (t >> 6) & 31;
        int j = jt * 32 + l31;
        int kb = ks * 16 + q * 8;
        const float* p = W2 + (size_t)kb * 256 + j;
#pragma unroll
        for (int e = 0; e < 8; ++e) v[e] = (f16)p[(size_t)e * 256];
    } else if (u < U_P0F) {                // W3F: W3 is [256][3], pad j>=3 with 0
        int t = u - U_W3F;
        int ks = t >> 6;
        int j = l31;
        int kb = ks * 16 + q * 8;
        if (j < 3) {
            const float* p = W3 + (size_t)kb * 3 + j;
#pragma unroll
            for (int e = 0; e < 8; ++e) v[e] = (f16)p[(size_t)e * 3];
        }
    } else if (u < U_B1F) {                // P0F: layer-1 A frag with hi/lo split + bias
        int t = u - U_P0F;
        int jt = t >> 6;
        int j = jt * 32 + l31;
        if (q == 0) {
            float w00 = W0[j], w01 = W0[1024 + j], bb = b0[j];
            f16 w00h = (f16)w00, w01h = (f16)w01, bh = (f16)bb;
            v[0] = w00h; v[1] = w01h; v[2] = bh;
            v[3] = w00h; v[4] = w01h;                       // pair with x_lo
            v[5] = (f16)(w00 - (float)w00h);                // w_lo * x_hi
            v[6] = (f16)(w01 - (float)w01h);
            v[7] = (f16)(bb - (float)bh);                   // bias residual * 1
        }
    } else if (u < U_B2F) {                // B1F
        int t = u - U_B1F;
        int jt = t >> 6;
        int j = jt * 32 + l31;
        if (q == 0) v[0] = (f16)b1[j];
    } else {                               // B2F
        int t = u - U_B2F;
        int jt = t >> 6;
        int j = jt * 32 + l31;
        if (q == 0) v[0] = (f16)b2[j];
    }
    ((f16x8*)ws)[u] = v;
}

// ---- LDS slab helpers. Slab rows: [m][k] f16, row stride rs bytes.
// XOR swizzle at 8-byte (2-dword) granularity: phys_dw = dw ^ ((m&15)<<1).
// 2-way-max bank conflicts (free) for both b64 writes and reads.
__device__ __forceinline__ void slab_write4(unsigned char* lds, int m, int dw /*even*/,
                                            int rs, f16x4 val)
{
    int s = (m & 15) << 1;
    *(f16x4*)(lds + (size_t)m * rs + (size_t)((dw ^ s) << 2)) = val;
}

__device__ __forceinline__ f16x8 slab_read8(const unsigned char* lds, int m, int dw /*mult of 4*/,
                                            int rs)
{
    int s = (m & 15) << 1;
    f16x4 lo = *(const f16x4*)(lds + (size_t)m * rs + (size_t)((dw ^ s) << 2));
    f16x4 hi = *(const f16x4*)(lds + (size_t)m * rs + (size_t)(((dw + 2) ^ s) << 2));
    union { f16x8 v; f16x4 p[2]; } u;
    u.p[0] = lo; u.p[1] = hi;
    return u.v;
}

__device__ __forceinline__ f16x4 relu_pack4(const f32x16& d, int t)
{
    f16x4 pk;
#pragma unroll
    for (int r = 0; r < 4; ++r) {
        float v = d[4 * t + r];
        pk[r] = (f16)(v > 0.f ? v : 0.f);
    }
    return pk;
}

__global__ __launch_bounds__(1024, 4)
void mlp_kernel(const float* __restrict__ X, const float* __restrict__ b3,
                const f16* __restrict__ ws, float* __restrict__ out)
{
    const f16x8* W1F = (const f16x8*)ws + U_W1F;
    const f16x8* W2F = (const f16x8*)ws + U_W2F;
    const f16x8* W3F = (const f16x8*)ws + U_W3F;
    const f16x8* P0F = (const f16x8*)ws + U_P0F;
    const f16x8* B1F = (const f16x8*)ws + U_B1F;
    const f16x8* B2F = (const f16x8*)ws + U_B2F;

    __shared__ __align__(16) unsigned char lds[65536];

    const int tid  = threadIdx.x;
    const int w    = tid >> 6;       // wave 0..15
    const int lane = tid & 63;
    const int l31  = lane & 31;
    const int q    = lane >> 5;
    const size_t rowbase = (size_t)blockIdx.x * 128;

    f32x16 zero16;
#pragma unroll
    for (int i = 0; i < 16; ++i) zero16[i] = 0.f;

    // ones frag for bias-init MFMAs
    f16x8 ones;
#pragma unroll
    for (int e = 0; e < 8; ++e) ones[e] = (f16)0.f;
    if (q == 0) ones[0] = (f16)1.f;

    // This wave's two layer-1 m-tiles and their X frags (hi/lo split -> ~exact L1)
    const int mtbase = (w >> 3) * 2;
    f16x8 xfrag[2];
#pragma unroll
    for (int u = 0; u < 2; ++u) {
        f16x8 v;
#pragma unroll
        for (int e = 0; e < 8; ++e) v[e] = (f16)0.f;
        if (q == 0) {
            float2 xv = ((const float2*)X)[rowbase + (mtbase + u) * 32 + l31];
            f16 x0h = (f16)xv.x, x1h = (f16)xv.y;
            v[0] = x0h; v[1] = x1h; v[2] = (f16)1.f;
            v[3] = (f16)(xv.x - (float)x0h);
            v[4] = (f16)(xv.y - (float)x1h);
            v[5] = x0h; v[6] = x1h; v[7] = (f16)1.f;
        }
        xfrag[u] = v;
    }

    // ---- layer-2 accumulators: wave w owns j-tile w (feats w*32..w*32+31),
    // all 4 m-tiles. Bias-initialized via MFMA with B1F.
    f32x16 acc2[4];
    {
        f32x16 binit = MFMA(B1F[w * 64 + lane], ones, zero16);
#pragma unroll
        for (int mt = 0; mt < 4; ++mt) acc2[mt] = binit;
    }

    // ---- fused layer1 + layer2: K chunked 4 x 256 through 64KB slab (rs=512B)
    for (int c = 0; c < 4; ++c) {
        // layer 1: chunk has 8 k1-tiles x 4 m-tiles = 32 MFMA units / 16 waves.
        // wave w: k1-tile (w&7), m-tiles mtbase..mtbase+1.
        {
            f16x8 af1 = P0F[(c * 8 + (w & 7)) * 64 + lane];
#pragma unroll
            for (int u = 0; u < 2; ++u) {
                f32x16 d = MFMA(af1, xfrag[u], zero16);
                int m = (mtbase + u) * 32 + l31;          // D col -> batch row
                int kb = (w & 7) * 32 + 4 * q;            // D row -> h1 feat (chunk-local)
#pragma unroll
                for (int t = 0; t < 4; ++t)
                    slab_write4(lds, m, (kb + 8 * t) >> 1, 512, relu_pack4(d, t));
            }
        }
        __syncthreads();
        // layer 2 partial K: 16 k-steps; A = W1F stream (L2), B = slab
        for (int ks = 0; ks < 16; ++ks) {
            f16x8 af = W1F[(w * 64 + c * 16 + ks) * 64 + lane];
#pragma unroll
            for (int mt = 0; mt < 4; ++mt) {
                f16x8 bf = slab_read8(lds, mt * 32 + l31, (ks * 16 + q * 8) >> 1, 512);
                acc2[mt] = MFMA(af, bf, acc2[mt]);
            }
        }
        __syncthreads();
    }

    // ---- tail: process row-halves so h2 (64 rows x 512 feats = 64KB) fits LDS
    const int jt3  = w >> 1;                 // layer-3 j-tile, 8 tiles x 2 waves
    const int mloc = (w & 1) * 32 + l31;     // local row within the 64-row half
#pragma unroll
    for (int mh = 0; mh < 2; ++mh) {
        // stage h2 rows [mh*64, mh*64+64): wave w writes feats w*32..w*32+31
#pragma unroll
        for (int u = 0; u < 2; ++u) {
            int mt = mh * 2 + u;
            int mrow = u * 32 + l31;
            int jb = w * 32 + 4 * q;
#pragma unroll
            for (int t = 0; t < 4; ++t)
                slab_write4(lds, mrow, (jb + 8 * t) >> 1, 1024, relu_pack4(acc2[mt], t));
        }
        __syncthreads();
        // layer 3 full-K (512): wave w -> (j-tile jt3, rows mloc)
        f32x16 acc3 = MFMA(B2F[jt3 * 64 + lane], ones, zero16);
        for (int ks = 0; ks < 32; ++ks) {
            f16x8 af = W2F[(jt3 * 32 + ks) * 64 + lane];
            f16x8 bf = slab_read8(lds, mloc, (ks * 16 + q * 8) >> 1, 1024);
            acc3 = MFMA(af, bf, acc3);
        }
        __syncthreads();
        // stage h3 (64 rows x 256 feats, rs=512B): wave writes its (jt3, mloc) tile
        {
            int jb = jt3 * 32 + 4 * q;
#pragma unroll
            for (int t = 0; t < 4; ++t)
                slab_write4(lds, mloc, (jb + 8 * t) >> 1, 512, relu_pack4(acc3, t));
        }
        __syncthreads();
        // layer 4: waves 0,1 compute the two 32-row tiles (j padded to 32, 3 valid)
        if (w < 2) {
            f32x16 acc4 = zero16;
            for (int ks = 0; ks < 16; ++ks) {
                f16x8 af = W3F[ks * 64 + lane];
                f16x8 bf = slab_read8(lds, w * 32 + l31, (ks * 16 + q * 8) >> 1, 512);
                acc4 = MFMA(af, bf, acc4);
            }
            if (q == 0) {
                size_t gm = rowbase + mh * 64 + w * 32 + l31;
                out[gm * 3 + 0] = acc4[0] + b3[0];
                out[gm * 3 + 1] = acc4[1] + b3[1];
                out[gm * 3 + 2] = acc4[2] + b3[2];
            }
        }
        __syncthreads();   // h2/h3 region reused by next mh iteration
    }
}

extern "C" void kernel_launch(void* const* d_in, const int* in_sizes, int n_in,
                              void* d_out, int out_size, void* d_ws, size_t ws_size,
                              hipStream_t stream)
{
    const float* X  = (const float*)d_in[0];
    const float* W0 = (const float*)d_in[1];
    const float* b0 = (const float*)d_in[2];
    const float* W1 = (const float*)d_in[3];
    const float* b1 = (const float*)d_in[4];
    const float* W2 = (const float*)d_in[5];
    const float* b2 = (const float*)d_in[6];
    const float* W3 = (const float*)d_in[7];
    const float* b3 = (const float*)d_in[8];
    f16* ws = (f16*)d_ws;

    int N = in_sizes[0] / 2;          // 262144
    int nblk = N / 128;               // 2048

    prep_kernel<<<(U_TOTAL + 255) / 256, 256, 0, stream>>>(W0, b0, W1, b1, W2, b2, W3, ws);
    mlp_kernel<<<nblk, 1024, 0, stream>>>(X, b3, ws, (float*)d_out);
}

// Round 3
// 738.717 us; speedup vs baseline: 1.0070x; 1.0070x over previous
//
#include <hip/hip_runtime.h>

// Fused 4-layer MLP (2 -> 1024 -> 512 -> 256 -> 3), N = 262144, fp32 I/O.
// R3: 1024 threads (16 waves), 128 rows/block, 2048 blocks.
// Register discipline: acc2[4] (64 AGPR) is the ONLY big live set; xfrag is
// 4 regs; tail phases fully sequenced so acc3/acc4 never overlap acc2 pipelines.
// fp16 MFMA 32x32x16, fp32 accumulate, transposed layers D[feat][batch].

typedef _Float16 f16;
typedef f16 f16x8 __attribute__((ext_vector_type(8)));
typedef f16 f16x4 __attribute__((ext_vector_type(4)));
typedef float f32x16 __attribute__((ext_vector_type(16)));

#define MFMA(a, b, c) __builtin_amdgcn_mfma_f32_32x32x16_f16((a), (b), (c), 0, 0, 0)

// ws layout in 16-byte units (f16x8):
//  W1F : [16 jt][64 ks][64 lane]            ->      0 .. 65536
//  W2F : [ 8 jt][32 ks][64 lane]            ->  65536 .. 81920
//  W3F : [16 ks][64 lane]                   ->  81920 .. 82944
//  P0F : [32 k1t][64 lane] (layer1 A frag)  ->  82944 .. 84992
//  B1F : [16 jt][64 lane]                   ->  84992 .. 86016
//  B2F : [ 8 jt][64 lane]                   ->  86016 .. 86528
#define U_W1F 0
#define U_W2F 65536
#define U_W3F 81920
#define U_P0F 82944
#define U_B1F 84992
#define U_B2F 86016
#define U_TOTAL 86528

__global__ void prep_kernel(const float* __restrict__ W0, const float* __restrict__ b0,
                            const float* __restrict__ W1, const float* __restrict__ b1,
                            const float* __restrict__ W2, const float* __restrict__ b2,
                            const float* __restrict__ W3, f16* __restrict__ ws)
{
    int u = blockIdx.x * 256 + threadIdx.x;
    if (u >= U_TOTAL) return;
    int lane = u & 63;
    int l31 = lane & 31;
    int q = lane >> 5;
    f16x8 v;
#pragma unroll
    for (int e = 0; e < 8; ++e) v[e] = (f16)0.f;

    if (u < U_W2F) {                       // W1F: W1 is [1024][512]
        int jt = u >> 12, ks = (u >> 6) & 63;
        int j = jt * 32 + l31;
        int kb = ks * 16 + q * 8;
        const float* p = W1 + (size_t)kb * 512 + j;
#pragma unroll
        for (int e = 0; e < 8; ++e) v[e] = (f16)p[(size_t)e * 512];
    } else if (u < U_W3F) {                // W2F: W2 is [512][256]
        int t = u - U_W2F;
        int jt = t >> 11, ks = (t >> 6) & 31;
        int j = jt * 32 + l31;
        int kb = ks * 16 + q * 8;
        const float* p = W2 + (size_t)kb * 256 + j;
#pragma unroll
        for (int e = 0; e < 8; ++e) v[e] = (f16)p[(size_t)e * 256];
    } else if (u < U_P0F) {                // W3F: W3 is [256][3], pad j>=3 with 0
        int t = u - U_W3F;
        int ks = t >> 6;
        int j = l31;
        int kb = ks * 16 + q * 8;
        if (j < 3) {
            const float* p = W3 + (size_t)kb * 3 + j;
#pragma unroll
            for (int e = 0; e < 8; ++e) v[e] = (f16)p[(size_t)e * 3];
        }
    } else if (u < U_B1F) {                // P0F: layer-1 A frag with hi/lo split + bias
        int t = u - U_P0F;
        int jt = t >> 6;
        int j = jt * 32 + l31;
        if (q == 0) {
            float w00 = W0[j], w01 = W0[1024 + j], bb = b0[j];
            f16 w00h = (f16)w00, w01h = (f16)w01, bh = (f16)bb;
            v[0] = w00h; v[1] = w01h; v[2] = bh;
            v[3] = w00h; v[4] = w01h;                       // pair with x_lo
            v[5] = (f16)(w00 - (float)w00h);                // w_lo * x_hi
            v[6] = (f16)(w01 - (float)w01h);
            v[7] = (f16)(bb - (float)bh);                   // bias residual * 1
        }
    } else if (u < U_B2F) {                // B1F
        int t = u - U_B1F;
        int jt = t >> 6;
        int j = jt * 32 + l31;
        if (q == 0) v[0] = (f16)b1[j];
    } else {                               // B2F
        int t = u - U_B2F;
        int jt = t >> 6;
        int j = jt * 32 + l31;
        if (q == 0) v[0] = (f16)b2[j];
    }
    ((f16x8*)ws)[u] = v;
}

// ---- LDS slab helpers. Slab rows: [m][k] f16, row stride rs bytes.
// XOR swizzle at 8-byte granularity: phys_dw = dw ^ ((m&15)<<1).
// 2-way-max bank conflicts (free) for both b64 writes and reads.
__device__ __forceinline__ void slab_write4(unsigned char* lds, int m, int dw /*even*/,
                                            int rs, f16x4 val)
{
    int s = (m & 15) << 1;
    *(f16x4*)(lds + (size_t)m * rs + (size_t)((dw ^ s) << 2)) = val;
}

__device__ __forceinline__ f16x8 slab_read8(const unsigned char* lds, int m, int dw /*mult of 4*/,
                                            int rs)
{
    int s = (m & 15) << 1;
    f16x4 lo = *(const f16x4*)(lds + (size_t)m * rs + (size_t)((dw ^ s) << 2));
    f16x4 hi = *(const f16x4*)(lds + (size_t)m * rs + (size_t)(((dw + 2) ^ s) << 2));
    union { f16x8 v; f16x4 p[2]; } u;
    u.p[0] = lo; u.p[1] = hi;
    return u.v;
}

__device__ __forceinline__ f16x4 relu_pack4(const f32x16& d, int t)
{
    f16x4 pk;
#pragma unroll
    for (int r = 0; r < 4; ++r) {
        float v = d[4 * t + r];
        pk[r] = (f16)(v > 0.f ? v : 0.f);
    }
    return pk;
}

__global__ __launch_bounds__(1024, 4)
void mlp_kernel(const float* __restrict__ X, const float* __restrict__ b3,
                const f16* __restrict__ ws, float* __restrict__ out)
{
    const f16x8* W1F = (const f16x8*)ws + U_W1F;
    const f16x8* W2F = (const f16x8*)ws + U_W2F;
    const f16x8* W3F = (const f16x8*)ws + U_W3F;
    const f16x8* P0F = (const f16x8*)ws + U_P0F;
    const f16x8* B1F = (const f16x8*)ws + U_B1F;
    const f16x8* B2F = (const f16x8*)ws + U_B2F;

    __shared__ __align__(16) unsigned char lds[65536];

    const int tid  = threadIdx.x;
    const int w    = tid >> 6;       // wave 0..15
    const int lane = tid & 63;
    const int l31  = lane & 31;
    const int q    = lane >> 5;
    const size_t rowbase = (size_t)blockIdx.x * 128;

    f32x16 zero16;
#pragma unroll
    for (int i = 0; i < 16; ++i) zero16[i] = 0.f;

    // ones frag for bias-init MFMAs (4 regs)
    f16x8 ones;
#pragma unroll
    for (int e = 0; e < 8; ++e) ones[e] = (f16)0.f;
    if (q == 0) ones[0] = (f16)1.f;

    // Layer-1 work split: 8 k1-tiles x 4 m-tiles per chunk = 32 units = 16 waves x 2.
    // Wave w: m-tile mtL1 = w&3, k1-tiles 2*(w>>2), 2*(w>>2)+1. xfrag = 4 regs.
    const int mtL1 = w & 3;
    f16x8 xfrag;
    {
        f16x8 v;
#pragma unroll
        for (int e = 0; e < 8; ++e) v[e] = (f16)0.f;
        if (q == 0) {
            float2 xv = ((const float2*)X)[rowbase + mtL1 * 32 + l31];
            f16 x0h = (f16)xv.x, x1h = (f16)xv.y;
            v[0] = x0h; v[1] = x1h; v[2] = (f16)1.f;
            v[3] = (f16)(xv.x - (float)x0h);
            v[4] = (f16)(xv.y - (float)x1h);
            v[5] = x0h; v[6] = x1h; v[7] = (f16)1.f;
        }
        xfrag = v;
    }

    // Layer-2 accumulators: wave w owns j-tile w (feats w*32..+31), 4 m-tiles.
    f32x16 acc2[4];
    {
        f32x16 binit = MFMA(B1F[w * 64 + lane], ones, zero16);
#pragma unroll
        for (int mt = 0; mt < 4; ++mt) acc2[mt] = binit;
    }

    // ---- fused layer1 + layer2: K chunked 4 x 256 through slab (128 rows, rs=512B)
    for (int c = 0; c < 4; ++c) {
        // layer 1: wave computes 2 (k1,mt) units
#pragma unroll
        for (int u = 0; u < 2; ++u) {
            int k1loc = (w >> 2) * 2 + u;
            f16x8 af1 = P0F[(c * 8 + k1loc) * 64 + lane];
            f32x16 d = MFMA(af1, xfrag, zero16);
            int m = mtL1 * 32 + l31;              // D col -> batch row
            int kb = k1loc * 32 + 4 * q;          // D row -> h1 feat (chunk-local)
#pragma unroll
            for (int t = 0; t < 4; ++t)
                slab_write4(lds, m, (kb + 8 * t) >> 1, 512, relu_pack4(d, t));
        }
        __syncthreads();
        // layer 2 partial K: 16 ks; one af (jt = w), 4 bf per ks
        for (int ks = 0; ks < 16; ++ks) {
            f16x8 af = W1F[(w * 64 + c * 16 + ks) * 64 + lane];
#pragma unroll
            for (int mt = 0; mt < 4; ++mt) {
                f16x8 bf = slab_read8(lds, mt * 32 + l31, (ks * 16 + q * 8) >> 1, 512);
                acc2[mt] = MFMA(af, bf, acc2[mt]);
            }
        }
        __syncthreads();
    }

    // ---- tail: two row-halves; each phase fully sequenced (no acc overlap)
    const int jt3  = w >> 1;                 // layer-3 j-tile (8 tiles x 2 waves)
    const int mloc = (w & 1) * 32 + l31;     // row within the 64-row half
#pragma unroll
    for (int mh = 0; mh < 2; ++mh) {
        // stage h2 rows [mh*64, +64): wave w writes feats w*32..+31 (rs=1024)
#pragma unroll
        for (int u = 0; u < 2; ++u) {
            int mrow = u * 32 + l31;
            int jb = w * 32 + 4 * q;
#pragma unroll
            for (int t = 0; t < 4; ++t)
                slab_write4(lds, mrow, (jb + 8 * t) >> 1, 1024,
                            relu_pack4(acc2[mh * 2 + u], t));
        }
        __syncthreads();
        // layer 3 full-K (512): wave w -> (jt3, rows mloc)
        f32x16 acc3 = MFMA(B2F[jt3 * 64 + lane], ones, zero16);
        for (int ks = 0; ks < 32; ++ks) {
            f16x8 af = W2F[(jt3 * 32 + ks) * 64 + lane];
            f16x8 bf = slab_read8(lds, mloc, (ks * 16 + q * 8) >> 1, 1024);
            acc3 = MFMA(af, bf, acc3);
        }
        __syncthreads();
        // stage h3 (64 rows x 256 feats, rs=512B)
        {
            int jb = jt3 * 32 + 4 * q;
#pragma unroll
            for (int t = 0; t < 4; ++t)
                slab_write4(lds, mloc, (jb + 8 * t) >> 1, 512, relu_pack4(acc3, t));
        }
        __syncthreads();
        // layer 4: waves 0,1 -> the two 32-row tiles (j padded to 32, 3 valid)
        if (w < 2) {
            f32x16 acc4 = zero16;
            for (int ks = 0; ks < 16; ++ks) {
                f16x8 af = W3F[ks * 64 + lane];
                f16x8 bf = slab_read8(lds, w * 32 + l31, (ks * 16 + q * 8) >> 1, 512);
                acc4 = MFMA(af, bf, acc4);
            }
            if (q == 0) {
                size_t gm = rowbase + mh * 64 + w * 32 + l31;
                out[gm * 3 + 0] = acc4[0] + b3[0];
                out[gm * 3 + 1] = acc4[1] + b3[1];
                out[gm * 3 + 2] = acc4[2] + b3[2];
            }
        }
        __syncthreads();   // slab reused by next half
    }
}

extern "C" void kernel_launch(void* const* d_in, const int* in_sizes, int n_in,
                              void* d_out, int out_size, void* d_ws, size_t ws_size,
                              hipStream_t stream)
{
    const float* X  = (const float*)d_in[0];
    const float* W0 = (const float*)d_in[1];
    const float* b0 = (const float*)d_in[2];
    const float* W1 = (const float*)d_in[3];
    const float* b1 = (const float*)d_in[4];
    const float* W2 = (const float*)d_in[5];
    const float* b2 = (const float*)d_in[6];
    const float* W3 = (const float*)d_in[7];
    const float* b3 = (const float*)d_in[8];
    f16* ws = (f16*)d_ws;

    int N = in_sizes[0] / 2;          // 262144
    int nblk = N / 128;               // 2048

    prep_kernel<<<(U_TOTAL + 255) / 256, 256, 0, stream>>>(W0, b0, W1, b1, W2, b2, W3, ws);
    mlp_kernel<<<nblk, 1024, 0, stream>>>(X, b3, ws, (float*)d_out);
}

// Round 4
// 732.374 us; speedup vs baseline: 1.0157x; 1.0087x over previous
//
#include <hip/hip_runtime.h>

// Fused 4-layer MLP (2 -> 1024 -> 512 -> 256 -> 3), N = 262144, fp32 I/O.
// R4: identical structure to R3, but __launch_bounds__(1024,3).
// Rationale: acc2 (64 f32/thread) is half the register file at 4 waves/SIMD,
// leaving only 64 arch VGPRs -> 1.8 GB scratch spill (R2/R3 counters).
// 3 waves/SIMD gives 170 regs/thread: 64 AGPR acc + ~106 arch, spill-free.

typedef _Float16 f16;
typedef f16 f16x8 __attribute__((ext_vector_type(8)));
typedef f16 f16x4 __attribute__((ext_vector_type(4)));
typedef float f32x16 __attribute__((ext_vector_type(16)));

#define MFMA(a, b, c) __builtin_amdgcn_mfma_f32_32x32x16_f16((a), (b), (c), 0, 0, 0)

// ws layout in 16-byte units (f16x8):
//  W1F : [16 jt][64 ks][64 lane]            ->      0 .. 65536
//  W2F : [ 8 jt][32 ks][64 lane]            ->  65536 .. 81920
//  W3F : [16 ks][64 lane]                   ->  81920 .. 82944
//  P0F : [32 k1t][64 lane] (layer1 A frag)  ->  82944 .. 84992
//  B1F : [16 jt][64 lane]                   ->  84992 .. 86016
//  B2F : [ 8 jt][64 lane]                   ->  86016 .. 86528
#define U_W1F 0
#define U_W2F 65536
#define U_W3F 81920
#define U_P0F 82944
#define U_B1F 84992
#define U_B2F 86016
#define U_TOTAL 86528

__global__ void prep_kernel(const float* __restrict__ W0, const float* __restrict__ b0,
                            const float* __restrict__ W1, const float* __restrict__ b1,
                            const float* __restrict__ W2, const float* __restrict__ b2,
                            const float* __restrict__ W3, f16* __restrict__ ws)
{
    int u = blockIdx.x * 256 + threadIdx.x;
    if (u >= U_TOTAL) return;
    int lane = u & 63;
    int l31 = lane & 31;
    int q = lane >> 5;
    f16x8 v;
#pragma unroll
    for (int e = 0; e < 8; ++e) v[e] = (f16)0.f;

    if (u < U_W2F) {                       // W1F: W1 is [1024][512]
        int jt = u >> 12, ks = (u >> 6) & 63;
        int j = jt * 32 + l31;
        int kb = ks * 16 + q * 8;
        const float* p = W1 + (size_t)kb * 512 + j;
#pragma unroll
        for (int e = 0; e < 8; ++e) v[e] = (f16)p[(size_t)e * 512];
    } else if (u < U_W3F) {                // W2F: W2 is [512][256]
        int t = u - U_W2F;
        int jt = t >> 11, ks = (t >> 6) & 31;
        int j = jt * 32 + l31;
        int kb = ks * 16 + q * 8;
        const float* p = W2 + (size_t)kb * 256 + j;
#pragma unroll
        for (int e = 0; e < 8; ++e) v[e] = (f16)p[(size_t)e * 256];
    } else if (u < U_P0F) {                // W3F: W3 is [256][3], pad j>=3 with 0
        int t = u - U_W3F;
        int ks = t >> 6;
        int j = l31;
        int kb = ks * 16 + q * 8;
        if (j < 3) {
            const float* p = W3 + (size_t)kb * 3 + j;
#pragma unroll
            for (int e = 0; e < 8; ++e) v[e] = (f16)p[(size_t)e * 3];
        }
    } else if (u < U_B1F) {                // P0F: layer-1 A frag with hi/lo split + bias
        int t = u - U_P0F;
        int jt = t >> 6;
        int j = jt * 32 + l31;
        if (q == 0) {
            float w00 = W0[j], w01 = W0[1024 + j], bb = b0[j];
            f16 w00h = (f16)w00, w01h = (f16)w01, bh = (f16)bb;
            v[0] = w00h; v[1] = w01h; v[2] = bh;
            v[3] = w00h; v[4] = w01h;                       // pair with x_lo
            v[5] = (f16)(w00 - (float)w00h);                // w_lo * x_hi
            v[6] = (f16)(w01 - (float)w01h);
            v[7] = (f16)(bb - (float)bh);                   // bias residual * 1
        }
    } else if (u < U_B2F) {                // B1F
        int t = u - U_B1F;
        int jt = t >> 6;
        int j = jt * 32 + l31;
        if (q == 0) v[0] = (f16)b1[j];
    } else {                               // B2F
        int t = u - U_B2F;
        int jt = t >> 6;
        int j = jt * 32 + l31;
        if (q == 0) v[0] = (f16)b2[j];
    }
    ((f16x8*)ws)[u] = v;
}

// ---- LDS slab helpers. Slab rows: [m][k] f16, row stride rs bytes.
// XOR swizzle at 8-byte granularity: phys_dw = dw ^ ((m&15)<<1).
// 2-way-max bank conflicts (free) for both b64 writes and reads.
__device__ __forceinline__ void slab_write4(unsigned char* lds, int m, int dw /*even*/,
                                            int rs, f16x4 val)
{
    int s = (m & 15) << 1;
    *(f16x4*)(lds + (size_t)m * rs + (size_t)((dw ^ s) << 2)) = val;
}

__device__ __forceinline__ f16x8 slab_read8(const unsigned char* lds, int m, int dw /*mult of 4*/,
                                            int rs)
{
    int s = (m & 15) << 1;
    f16x4 lo = *(const f16x4*)(lds + (size_t)m * rs + (size_t)((dw ^ s) << 2));
    f16x4 hi = *(const f16x4*)(lds + (size_t)m * rs + (size_t)(((dw + 2) ^ s) << 2));
    union { f16x8 v; f16x4 p[2]; } u;
    u.p[0] = lo; u.p[1] = hi;
    return u.v;
}

__device__ __forceinline__ f16x4 relu_pack4(const f32x16& d, int t)
{
    f16x4 pk;
#pragma unroll
    for (int r = 0; r < 4; ++r) {
        float v = d[4 * t + r];
        pk[r] = (f16)(v > 0.f ? v : 0.f);
    }
    return pk;
}

__global__ __launch_bounds__(1024, 3)
void mlp_kernel(const float* __restrict__ X, const float* __restrict__ b3,
                const f16* __restrict__ ws, float* __restrict__ out)
{
    const f16x8* W1F = (const f16x8*)ws + U_W1F;
    const f16x8* W2F = (const f16x8*)ws + U_W2F;
    const f16x8* W3F = (const f16x8*)ws + U_W3F;
    const f16x8* P0F = (const f16x8*)ws + U_P0F;
    const f16x8* B1F = (const f16x8*)ws + U_B1F;
    const f16x8* B2F = (const f16x8*)ws + U_B2F;

    __shared__ __align__(16) unsigned char lds[65536];

    const int tid  = threadIdx.x;
    const int w    = tid >> 6;       // wave 0..15
    const int lane = tid & 63;
    const int l31  = lane & 31;
    const int q    = lane >> 5;
    const size_t rowbase = (size_t)blockIdx.x * 128;

    f32x16 zero16;
#pragma unroll
    for (int i = 0; i < 16; ++i) zero16[i] = 0.f;

    // ones frag for bias-init MFMAs (4 regs)
    f16x8 ones;
#pragma unroll
    for (int e = 0; e < 8; ++e) ones[e] = (f16)0.f;
    if (q == 0) ones[0] = (f16)1.f;

    // Layer-1 work split: 8 k1-tiles x 4 m-tiles per chunk = 32 units = 16 waves x 2.
    // Wave w: m-tile mtL1 = w&3, k1-tiles 2*(w>>2), 2*(w>>2)+1. xfrag = 4 regs.
    const int mtL1 = w & 3;
    f16x8 xfrag;
    {
        f16x8 v;
#pragma unroll
        for (int e = 0; e < 8; ++e) v[e] = (f16)0.f;
        if (q == 0) {
            float2 xv = ((const float2*)X)[rowbase + mtL1 * 32 + l31];
            f16 x0h = (f16)xv.x, x1h = (f16)xv.y;
            v[0] = x0h; v[1] = x1h; v[2] = (f16)1.f;
            v[3] = (f16)(xv.x - (float)x0h);
            v[4] = (f16)(xv.y - (float)x1h);
            v[5] = x0h; v[6] = x1h; v[7] = (f16)1.f;
        }
        xfrag = v;
    }

    // Layer-2 accumulators: wave w owns j-tile w (feats w*32..+31), 4 m-tiles.
    f32x16 acc2[4];
    {
        f32x16 binit = MFMA(B1F[w * 64 + lane], ones, zero16);
#pragma unroll
        for (int mt = 0; mt < 4; ++mt) acc2[mt] = binit;
    }

    // ---- fused layer1 + layer2: K chunked 4 x 256 through slab (128 rows, rs=512B)
    for (int c = 0; c < 4; ++c) {
        // layer 1: wave computes 2 (k1,mt) units
#pragma unroll
        for (int u = 0; u < 2; ++u) {
            int k1loc = (w >> 2) * 2 + u;
            f16x8 af1 = P0F[(c * 8 + k1loc) * 64 + lane];
            f32x16 d = MFMA(af1, xfrag, zero16);
            int m = mtL1 * 32 + l31;              // D col -> batch row
            int kb = k1loc * 32 + 4 * q;          // D row -> h1 feat (chunk-local)
#pragma unroll
            for (int t = 0; t < 4; ++t)
                slab_write4(lds, m, (kb + 8 * t) >> 1, 512, relu_pack4(d, t));
        }
        __syncthreads();
        // layer 2 partial K: 16 ks; one af (jt = w), 4 bf per ks
        for (int ks = 0; ks < 16; ++ks) {
            f16x8 af = W1F[(w * 64 + c * 16 + ks) * 64 + lane];
#pragma unroll
            for (int mt = 0; mt < 4; ++mt) {
                f16x8 bf = slab_read8(lds, mt * 32 + l31, (ks * 16 + q * 8) >> 1, 512);
                acc2[mt] = MFMA(af, bf, acc2[mt]);
            }
        }
        __syncthreads();
    }

    // ---- tail: two row-halves; each phase fully sequenced (no acc overlap)
    const int jt3  = w >> 1;                 // layer-3 j-tile (8 tiles x 2 waves)
    const int mloc = (w & 1) * 32 + l31;     // row within the 64-row half
#pragma unroll
    for (int mh = 0; mh < 2; ++mh) {
        // stage h2 rows [mh*64, +64): wave w writes feats w*32..+31 (rs=1024)
#pragma unroll
        for (int u = 0; u < 2; ++u) {
            int mrow = u * 32 + l31;
            int jb = w * 32 + 4 * q;
#pragma unroll
            for (int t = 0; t < 4; ++t)
                slab_write4(lds, mrow, (jb + 8 * t) >> 1, 1024,
                            relu_pack4(acc2[mh * 2 + u], t));
        }
        __syncthreads();
        // layer 3 full-K (512): wave w -> (jt3, rows mloc)
        f32x16 acc3 = MFMA(B2F[jt3 * 64 + lane], ones, zero16);
        for (int ks = 0; ks < 32; ++ks) {
            f16x8 af = W2F[(jt3 * 32 + ks) * 64 + lane];
            f16x8 bf = slab_read8(lds, mloc, (ks * 16 + q * 8) >> 1, 1024);
            acc3 = MFMA(af, bf, acc3);
        }
        __syncthreads();
        // stage h3 (64 rows x 256 feats, rs=512B)
        {
            int jb = jt3 * 32 + 4 * q;
#pragma unroll
            for (int t = 0; t < 4; ++t)
                slab_write4(lds, mloc, (jb + 8 * t) >> 1, 512, relu_pack4(acc3, t));
        }
        __syncthreads();
        // layer 4: waves 0,1 -> the two 32-row tiles (j padded to 32, 3 valid)
        if (w < 2) {
            f32x16 acc4 = zero16;
            for (int ks = 0; ks < 16; ++ks) {
                f16x8 af = W3F[ks * 64 + lane];
                f16x8 bf = slab_read8(lds, w * 32 + l31, (ks * 16 + q * 8) >> 1, 512);
                acc4 = MFMA(af, bf, acc4);
            }
            if (q == 0) {
                size_t gm = rowbase + mh * 64 + w * 32 + l31;
                out[gm * 3 + 0] = acc4[0] + b3[0];
                out[gm * 3 + 1] = acc4[1] + b3[1];
                out[gm * 3 + 2] = acc4[2] + b3[2];
            }
        }
        __syncthreads();   // slab reused by next half
    }
}

extern "C" void kernel_launch(void* const* d_in, const int* in_sizes, int n_in,
                              void* d_out, int out_size, void* d_ws, size_t ws_size,
                              hipStream_t stream)
{
    const float* X  = (const float*)d_in[0];
    const float* W0 = (const float*)d_in[1];
    const float* b0 = (const float*)d_in[2];
    const float* W1 = (const float*)d_in[3];
    const float* b1 = (const float*)d_in[4];
    const float* W2 = (const float*)d_in[5];
    const float* b2 = (const float*)d_in[6];
    const float* W3 = (const float*)d_in[7];
    const float* b3 = (const float*)d_in[8];
    f16* ws = (f16*)d_ws;

    int N = in_sizes[0] / 2;          // 262144
    int nblk = N / 128;               // 2048

    prep_kernel<<<(U_TOTAL + 255) / 256, 256, 0, stream>>>(W0, b0, W1, b1, W2, b2, W3, ws);
    mlp_kernel<<<nblk, 1024, 0, stream>>>(X, b3, ws, (float*)d_out);
}